// Round 6
// baseline (266.175 us; speedup 1.0000x reference)
//
#include <hip/hip_runtime.h>
#include <hip/hip_bf16.h>
#include <stdint.h>

// Gram matrix: G = X @ X^T, X = [512, 65536] fp32, out = [512, 512] fp32.
// Round 6: r5 three-kernel plan, GEMM occupancy 2->4 blocks/CU.
//   K1 convert: X fp32 -> bf16 into d_ws (67 MB), pure BW (~33 us).
//   K2 gemm:    m97 structure (128x128 tile, 256 thr, width-16
//               global_load_lds, 2-barrier K-loop). Symmetric grid, now
//               1024 blocks (= 4/CU, 16 waves/CU): diag 4 tiles x 64 chunks
//               (KC=1024, 32 iters) first, upper 6 tiles x 128 chunks
//               (KC=512, 16 iters). Every block stages exactly 256 KB ->
//               balanced on the binding (memory) resource. Logical staged
//               traffic unchanged (256 MB, LLC-hot).
//   K3 mirror:  copy upper tiles transposed into lower (1 MB).
// r5 profile note: top dispatches are the harness's 536 MB ws-poison fills
// (77 us, fixed overhead ~130 us of dur) — our kernels are each <77 us.
// GEMM was latency-bound at 2 blocks/CU; this round quadruples resident
// blocks so cross-block phase overlap (m114) hides the barrier vmcnt drain.
// Fallback if ws_size < 64 MiB: r1's fused kernel (known-good 135 us).

typedef short bf16x8 __attribute__((ext_vector_type(8)));   // 8 bf16 = 4 VGPRs
typedef float f32x4  __attribute__((ext_vector_type(4)));   // MFMA acc

#define HW    65536
#define CDIM  512

__device__ __forceinline__ short f2bf(float f) {
    __hip_bfloat16 h = __float2bfloat16(f);   // RNE
    short s;
    __builtin_memcpy(&s, &h, sizeof(short));
    return s;
}

__device__ __forceinline__ bf16x8 cvt8(float4 a, float4 b) {
    bf16x8 v;
    v[0] = f2bf(a.x); v[1] = f2bf(a.y); v[2] = f2bf(a.z); v[3] = f2bf(a.w);
    v[4] = f2bf(b.x); v[5] = f2bf(b.y); v[6] = f2bf(b.z); v[7] = f2bf(b.w);
    return v;
}

// async 16B global->LDS copy (DMA; no VGPR round-trip). LDS dest must be
// wave-uniform base + lane*16 — our staging layout is exactly lane-linear
// (thread t -> LDS byte t*16, and t*16 + 4096 for the second issue).
typedef const __attribute__((address_space(1))) unsigned int gbl_u32;
typedef __attribute__((address_space(3))) unsigned int lds_u32;
__device__ __forceinline__ void async16(const void* g, void* l) {
    __builtin_amdgcn_global_load_lds((gbl_u32*)g, (lds_u32*)l, 16, 0, 0);
}

// ---------------- K1: fp32 -> bf16 convert ----------------
__global__ __launch_bounds__(256)
void cvt_kernel(const float* __restrict__ X, unsigned short* __restrict__ Xb) {
    const size_t i = ((size_t)blockIdx.x * 256 + threadIdx.x) * 8;
    float4 a = *(const float4*)(X + i);
    float4 b = *(const float4*)(X + i + 4);
    bf16x8 v = cvt8(a, b);
    *(bf16x8*)(Xb + i) = v;
}

// ---------------- K2: symmetric bf16 GEMM ----------------
__global__ __launch_bounds__(256)
void gram_bf16_kernel(const unsigned short* __restrict__ Xb,
                      float* __restrict__ out) {
    // block decode:
    //   p < 256 : diag tile ti=tj=p>>6, chunk=p&63,  KC=1024 (32 iters)
    //   p >= 256: upper tile o=(p-256)>>7, chunk=(p-256)&127, KC=512 (16 iters)
    const int p = blockIdx.x;
    int ti, tj, kbase, iters;
    if (p < 256) {
        ti = tj = p >> 6;
        kbase = (p & 63) * 1024;
        iters = 32;
    } else {
        const int q = p - 256;
        const int o = q >> 7;
        const int TI[6] = {0, 0, 0, 1, 1, 2};
        const int TJ[6] = {1, 2, 3, 2, 3, 3};
        ti = TI[o]; tj = TJ[o];
        kbase = (q & 127) * 512;
        iters = 16;
    }
    const bool diag = (ti == tj);

    __shared__ unsigned short As[128 * 32];   // 8 KB, unpadded (lane-linear,
    __shared__ unsigned short Bs[128 * 32];   // required by global_load_lds)

    const int t    = threadIdx.x;
    const int wave = t >> 6;
    const int lane = t & 63;
    const int wm   = wave & 1;                // 2x2 wave grid, 64x64 out each
    const int wn   = wave >> 1;
    const int fm   = lane & 15;
    const int kg   = lane >> 4;

    // staging: thread t covers LDS bytes t*16 (rows 0..63) and t*16+4096
    // (rows 64..127); row = t>>2, col8 = (t&3)*8 bf16.
    const int srow = t >> 2;
    const int scol = (t & 3) * 8;
    const unsigned short* gA = Xb + (size_t)(ti * 128 + srow) * HW + kbase + scol;
    const unsigned short* gB = Xb + (size_t)(tj * 128 + srow) * HW + kbase + scol;
    unsigned short* lA = As + srow * 32 + scol;     // byte ofs = t*16
    unsigned short* lB = Bs + srow * 32 + scol;
    const size_t rstep = (size_t)64 * HW;           // +64 panel rows

    // fragment offsets (A-operand: m = lane&15, k-group = lane>>4, 8 bf16)
    int a_off[4], b_off[4];
#pragma unroll
    for (int i = 0; i < 4; ++i) {
        a_off[i] = (wm * 64 + i * 16 + fm) * 32 + kg * 8;
        b_off[i] = (wn * 64 + i * 16 + fm) * 32 + kg * 8;
    }
    const unsigned short* Bbase = diag ? As : Bs;

    f32x4 acc[4][4];
#pragma unroll
    for (int i = 0; i < 4; ++i)
#pragma unroll
        for (int j = 0; j < 4; ++j)
            acc[i][j] = (f32x4){0.f, 0.f, 0.f, 0.f};

    for (int it = 0; it < iters; ++it) {
        const int ko = it * 32;
        // stage BK=32 slab: 2 issues per panel (rows 0..63, 64..127)
        async16(gA + ko,         lA);
        async16(gA + ko + rstep, lA + 64 * 32);
        if (!diag) {
            async16(gB + ko,         lB);
            async16(gB + ko + rstep, lB + 64 * 32);
        }
        __syncthreads();   // compiler drains vmcnt before s_barrier (m97)

        bf16x8 af[4], bfr[4];
#pragma unroll
        for (int i = 0; i < 4; ++i) af[i]  = *(const bf16x8*)(As + a_off[i]);
#pragma unroll
        for (int j = 0; j < 4; ++j) bfr[j] = *(const bf16x8*)(Bbase + b_off[j]);

#pragma unroll
        for (int i = 0; i < 4; ++i)
#pragma unroll
            for (int j = 0; j < 4; ++j)
                acc[i][j] = __builtin_amdgcn_mfma_f32_16x16x32_bf16(
                    af[i], bfr[j], acc[i][j], 0, 0, 0);

        __syncthreads();   // all waves done reading before next stage
    }

    // epilogue: row-major coalesced atomics (upper/diag tiles only)
    // C/D layout (verified m89/m91): col = lane&15, row = (lane>>4)*4 + reg
    const int orow0 = ti * 128 + wm * 64 + (lane >> 4) * 4;
    const int ocol0 = tj * 128 + wn * 64 + fm;
#pragma unroll
    for (int i = 0; i < 4; ++i)
#pragma unroll
        for (int j = 0; j < 4; ++j)
#pragma unroll
            for (int r = 0; r < 4; ++r)
                atomicAdd(out + (orow0 + i * 16 + r) * CDIM + ocol0 + j * 16,
                          acc[i][j][r]);
}

// ---------------- K3: mirror upper -> lower ----------------
__global__ __launch_bounds__(256)
void mirror_kernel(float* __restrict__ out) {
    const int id = blockIdx.x * 256 + threadIdx.x;   // 0..262143
    const int r = id >> 9;
    const int c = id & 511;
    if ((r >> 7) > (c >> 7))
        out[id] = out[c * CDIM + r];
}

// ---------------- fallback: r1 fused kernel (known-good 135 us) ----------------
#define FKC   2048
#define FBK   32
#define FLDSS 40

__global__ __launch_bounds__(256, 2)
void gram_fallback(const float* __restrict__ X, float* __restrict__ out) {
    const int tile  = blockIdx.x;
    const int ti    = tile >> 2;
    const int tj    = tile & 3;
    const int chunk = blockIdx.y;

    __shared__ short As[128 * FLDSS];
    __shared__ short Bs[128 * FLDSS];

    const int t    = threadIdx.x;
    const int wave = t >> 6;
    const int lane = t & 63;
    const int wm   = wave & 1;
    const int wn   = wave >> 1;

    const int srow  = t >> 1;
    const int shalf = (t & 1) * 16;
    const float* pa = X + (size_t)(ti * 128 + srow) * HW + chunk * FKC + shalf;
    const float* pb = X + (size_t)(tj * 128 + srow) * HW + chunk * FKC + shalf;
    short* wa = As + srow * FLDSS + shalf;
    short* wb = Bs + srow * FLDSS + shalf;

    const int fm = lane & 15;
    const int kg = lane >> 4;
    int a_off[4], b_off[4];
#pragma unroll
    for (int i = 0; i < 4; ++i) {
        a_off[i] = (wm * 64 + i * 16 + fm) * FLDSS + kg * 8;
        b_off[i] = (wn * 64 + i * 16 + fm) * FLDSS + kg * 8;
    }

    f32x4 acc[4][4];
#pragma unroll
    for (int i = 0; i < 4; ++i)
#pragma unroll
        for (int j = 0; j < 4; ++j)
            acc[i][j] = (f32x4){0.f, 0.f, 0.f, 0.f};

    for (int it = 0; it < FKC / FBK; ++it) {
        float4 a0 = *(const float4*)(pa + 0);
        float4 a1 = *(const float4*)(pa + 4);
        float4 a2 = *(const float4*)(pa + 8);
        float4 a3 = *(const float4*)(pa + 12);
        float4 b0 = *(const float4*)(pb + 0);
        float4 b1 = *(const float4*)(pb + 4);
        float4 b2 = *(const float4*)(pb + 8);
        float4 b3 = *(const float4*)(pb + 12);

        bf16x8 va0 = cvt8(a0, a1), va1 = cvt8(a2, a3);
        bf16x8 vb0 = cvt8(b0, b1), vb1 = cvt8(b2, b3);

        __syncthreads();
        *(bf16x8*)(wa + 0) = va0;
        *(bf16x8*)(wa + 8) = va1;
        *(bf16x8*)(wb + 0) = vb0;
        *(bf16x8*)(wb + 8) = vb1;
        __syncthreads();

        bf16x8 af[4], bfr[4];
#pragma unroll
        for (int i = 0; i < 4; ++i) af[i]  = *(const bf16x8*)(As + a_off[i]);
#pragma unroll
        for (int j = 0; j < 4; ++j) bfr[j] = *(const bf16x8*)(Bs + b_off[j]);

#pragma unroll
        for (int i = 0; i < 4; ++i)
#pragma unroll
            for (int j = 0; j < 4; ++j)
                acc[i][j] = __builtin_amdgcn_mfma_f32_16x16x32_bf16(
                    af[i], bfr[j], acc[i][j], 0, 0, 0);

        pa += FBK;
        pb += FBK;
    }

    const int orow0 = ti * 128 + wm * 64 + (lane >> 4) * 4;
    const int ocol0 = tj * 128 + wn * 64 + fm;
#pragma unroll
    for (int i = 0; i < 4; ++i)
#pragma unroll
        for (int j = 0; j < 4; ++j)
#pragma unroll
            for (int r = 0; r < 4; ++r)
                atomicAdd(out + (orow0 + i * 16 + r) * CDIM + ocol0 + j * 16,
                          acc[i][j][r]);
}

extern "C" void kernel_launch(void* const* d_in, const int* in_sizes, int n_in,
                              void* d_out, int out_size, void* d_ws, size_t ws_size,
                              hipStream_t stream) {
    const float* x = (const float*)d_in[0];
    float* out = (float*)d_out;
    const size_t need = (size_t)CDIM * HW * 2;   // 67,108,864 B bf16 copy

    hipMemsetAsync(d_out, 0, (size_t)out_size * sizeof(float), stream);

    if (ws_size >= need) {
        unsigned short* xb = (unsigned short*)d_ws;
        cvt_kernel<<<dim3(16384), dim3(256), 0, stream>>>(x, xb);
        gram_bf16_kernel<<<dim3(1024), dim3(256), 0, stream>>>(xb, out);
        mirror_kernel<<<dim3(1024), dim3(256), 0, stream>>>(out);
    } else {
        gram_fallback<<<dim3(16, 32), dim3(256), 0, stream>>>(x, out);
    }
}

// Round 7
// 248.184 us; speedup vs baseline: 1.0725x; 1.0725x over previous
//
#include <hip/hip_runtime.h>
#include <hip/hip_bf16.h>
#include <stdint.h>

// Gram matrix: G = X @ X^T, X = [512, 65536] fp32, out = [512, 512] fp32.
// Round 7: r5 three-kernel plan + XCD-AFFINITY block scheduling in the GEMM.
// r5/r6 analysis: staged logical bytes (256 MB) moved at only ~4.3 TB/s
// because consecutive blocks (p%8 -> different XCDs) worked different
// K-chunks — per-XCD L2 never saw the 4x panel re-read amplification.
// New decode: p = 8*q + x, all blocks with the same x work the SAME 1 MB
// K-slice (4 panels x 1024 cols) on XCD x -> slice fits L2 (4 MB), L2
// serves the amplification at 34.5 TB/s aggregate, HBM/LLC sees ~unique.
//   q<40: phase k=q/10, tile=q%10 (0-3 diag, 4-9 upper); q>=40: k=4+(q-40)/6,
//   upper tile only. Diag blocks take chunks {c, c+32} (same mod-8 class,
//   64 iters); upper blocks one chunk (32 iters). Grid 512 = 2 blocks/CU,
//   atomics back at the 8.4M floor (= grid x 128^2; r6 showed ~2us/M cost).
// K1 cvt (fp32->bf16 ws, ~33us) and K3 mirror unchanged from r5.
// Fallback if ws_size < 64 MiB: r1's fused kernel (known-good 135 us).

typedef short bf16x8 __attribute__((ext_vector_type(8)));   // 8 bf16 = 4 VGPRs
typedef float f32x4  __attribute__((ext_vector_type(4)));   // MFMA acc

#define HW    65536
#define CDIM  512

__device__ __forceinline__ short f2bf(float f) {
    __hip_bfloat16 h = __float2bfloat16(f);   // RNE
    short s;
    __builtin_memcpy(&s, &h, sizeof(short));
    return s;
}

__device__ __forceinline__ bf16x8 cvt8(float4 a, float4 b) {
    bf16x8 v;
    v[0] = f2bf(a.x); v[1] = f2bf(a.y); v[2] = f2bf(a.z); v[3] = f2bf(a.w);
    v[4] = f2bf(b.x); v[5] = f2bf(b.y); v[6] = f2bf(b.z); v[7] = f2bf(b.w);
    return v;
}

// async 16B global->LDS copy (DMA; no VGPR round-trip). LDS dest must be
// wave-uniform base + lane*16 — our staging layout is exactly lane-linear.
typedef const __attribute__((address_space(1))) unsigned int gbl_u32;
typedef __attribute__((address_space(3))) unsigned int lds_u32;
__device__ __forceinline__ void async16(const void* g, void* l) {
    __builtin_amdgcn_global_load_lds((gbl_u32*)g, (lds_u32*)l, 16, 0, 0);
}

// ---------------- K1: fp32 -> bf16 convert ----------------
__global__ __launch_bounds__(256)
void cvt_kernel(const float* __restrict__ X, unsigned short* __restrict__ Xb) {
    const size_t i = ((size_t)blockIdx.x * 256 + threadIdx.x) * 8;
    float4 a = *(const float4*)(X + i);
    float4 b = *(const float4*)(X + i + 4);
    bf16x8 v = cvt8(a, b);
    *(bf16x8*)(Xb + i) = v;
}

// ---------------- K2: symmetric bf16 GEMM, XCD-affine ----------------
__global__ __launch_bounds__(256)
void gram_bf16_kernel(const unsigned short* __restrict__ Xb,
                      float* __restrict__ out) {
    // p = 8*q + x.  x = XCD class; all blocks sharing x work the same
    // 1024-col K-slice simultaneously -> L2-resident panel slice.
    const int p = blockIdx.x;
    const int x = p & 7;
    const int q = p >> 3;
    int tile, k;
    if (q < 40) { k = q / 10; tile = q % 10; }
    else        { const int r = q - 40; k = 4 + r / 6; tile = 4 + r % 6; }

    int ti, tj, iters;
    if (tile < 4) {               // diag: chunks {c, c+32}, 64 iters
        ti = tj = tile;
        iters = 64;
    } else {                      // upper off-diag: one chunk, 32 iters
        const int TI[6] = {0, 0, 0, 1, 1, 2};
        const int TJ[6] = {1, 2, 3, 2, 3, 3};
        ti = TI[tile - 4]; tj = TJ[tile - 4];
        iters = 32;
    }
    const int kslice = (x + 8 * k) * 1024;    // base 1024-col chunk
    const bool diag = (tile < 4);

    __shared__ unsigned short As[128 * 32];   // 8 KB, unpadded (lane-linear,
    __shared__ unsigned short Bs[128 * 32];   // required by global_load_lds)

    const int t    = threadIdx.x;
    const int wave = t >> 6;
    const int lane = t & 63;
    const int wm   = wave & 1;                // 2x2 wave grid, 64x64 out each
    const int wn   = wave >> 1;
    const int fm   = lane & 15;
    const int kg   = lane >> 4;

    // staging: thread t covers LDS bytes t*16 (rows 0..63) and t*16+4096
    // (rows 64..127); row = t>>2, col8 = (t&3)*8 bf16.
    const int srow = t >> 2;
    const int scol = (t & 3) * 8;
    const unsigned short* gA = Xb + (size_t)(ti * 128 + srow) * HW + scol;
    const unsigned short* gB = Xb + (size_t)(tj * 128 + srow) * HW + scol;
    unsigned short* lA = As + srow * 32 + scol;     // byte ofs = t*16
    unsigned short* lB = Bs + srow * 32 + scol;
    const size_t rstep = (size_t)64 * HW;           // +64 panel rows

    // fragment offsets (A-operand: m = lane&15, k-group = lane>>4, 8 bf16)
    int a_off[4], b_off[4];
#pragma unroll
    for (int i = 0; i < 4; ++i) {
        a_off[i] = (wm * 64 + i * 16 + fm) * 32 + kg * 8;
        b_off[i] = (wn * 64 + i * 16 + fm) * 32 + kg * 8;
    }
    const unsigned short* Bbase = diag ? As : Bs;

    f32x4 acc[4][4];
#pragma unroll
    for (int i = 0; i < 4; ++i)
#pragma unroll
        for (int j = 0; j < 4; ++j)
            acc[i][j] = (f32x4){0.f, 0.f, 0.f, 0.f};

    for (int it = 0; it < iters; ++it) {
        // diag: iters 0..31 -> chunk c, 32..63 -> chunk c+32 (same mod-8).
        // upper: it<32 so the (it>>5) term is 0.
        const int ko = kslice + ((it & 31) << 5) + ((it >> 5) << 15);

        async16(gA + ko,         lA);
        async16(gA + ko + rstep, lA + 64 * 32);
        if (!diag) {
            async16(gB + ko,         lB);
            async16(gB + ko + rstep, lB + 64 * 32);
        }
        __syncthreads();   // compiler drains vmcnt before s_barrier (m97)

        bf16x8 af[4], bfr[4];
#pragma unroll
        for (int i = 0; i < 4; ++i) af[i]  = *(const bf16x8*)(As + a_off[i]);
#pragma unroll
        for (int j = 0; j < 4; ++j) bfr[j] = *(const bf16x8*)(Bbase + b_off[j]);

#pragma unroll
        for (int i = 0; i < 4; ++i)
#pragma unroll
            for (int j = 0; j < 4; ++j)
                acc[i][j] = __builtin_amdgcn_mfma_f32_16x16x32_bf16(
                    af[i], bfr[j], acc[i][j], 0, 0, 0);

        __syncthreads();   // all waves done reading before next stage
    }

    // epilogue: row-major coalesced atomics (upper/diag tiles only)
    // C/D layout (verified m89/m91): col = lane&15, row = (lane>>4)*4 + reg
    const int orow0 = ti * 128 + wm * 64 + (lane >> 4) * 4;
    const int ocol0 = tj * 128 + wn * 64 + fm;
#pragma unroll
    for (int i = 0; i < 4; ++i)
#pragma unroll
        for (int j = 0; j < 4; ++j)
#pragma unroll
            for (int r = 0; r < 4; ++r)
                atomicAdd(out + (orow0 + i * 16 + r) * CDIM + ocol0 + j * 16,
                          acc[i][j][r]);
}

// ---------------- K3: mirror upper -> lower ----------------
__global__ __launch_bounds__(256)
void mirror_kernel(float* __restrict__ out) {
    const int id = blockIdx.x * 256 + threadIdx.x;   // 0..262143
    const int r = id >> 9;
    const int c = id & 511;
    if ((r >> 7) > (c >> 7))
        out[id] = out[c * CDIM + r];
}

// ---------------- fallback: r1 fused kernel (known-good 135 us) ----------------
#define FKC   2048
#define FBK   32
#define FLDSS 40

__global__ __launch_bounds__(256, 2)
void gram_fallback(const float* __restrict__ X, float* __restrict__ out) {
    const int tile  = blockIdx.x;
    const int ti    = tile >> 2;
    const int tj    = tile & 3;
    const int chunk = blockIdx.y;

    __shared__ short As[128 * FLDSS];
    __shared__ short Bs[128 * FLDSS];

    const int t    = threadIdx.x;
    const int wave = t >> 6;
    const int lane = t & 63;
    const int wm   = wave & 1;
    const int wn   = wave >> 1;

    const int srow  = t >> 1;
    const int shalf = (t & 1) * 16;
    const float* pa = X + (size_t)(ti * 128 + srow) * HW + chunk * FKC + shalf;
    const float* pb = X + (size_t)(tj * 128 + srow) * HW + chunk * FKC + shalf;
    short* wa = As + srow * FLDSS + shalf;
    short* wb = Bs + srow * FLDSS + shalf;

    const int fm = lane & 15;
    const int kg = lane >> 4;
    int a_off[4], b_off[4];
#pragma unroll
    for (int i = 0; i < 4; ++i) {
        a_off[i] = (wm * 64 + i * 16 + fm) * FLDSS + kg * 8;
        b_off[i] = (wn * 64 + i * 16 + fm) * FLDSS + kg * 8;
    }

    f32x4 acc[4][4];
#pragma unroll
    for (int i = 0; i < 4; ++i)
#pragma unroll
        for (int j = 0; j < 4; ++j)
            acc[i][j] = (f32x4){0.f, 0.f, 0.f, 0.f};

    for (int it = 0; it < FKC / FBK; ++it) {
        float4 a0 = *(const float4*)(pa + 0);
        float4 a1 = *(const float4*)(pa + 4);
        float4 a2 = *(const float4*)(pa + 8);
        float4 a3 = *(const float4*)(pa + 12);
        float4 b0 = *(const float4*)(pb + 0);
        float4 b1 = *(const float4*)(pb + 4);
        float4 b2 = *(const float4*)(pb + 8);
        float4 b3 = *(const float4*)(pb + 12);

        bf16x8 va0 = cvt8(a0, a1), va1 = cvt8(a2, a3);
        bf16x8 vb0 = cvt8(b0, b1), vb1 = cvt8(b2, b3);

        __syncthreads();
        *(bf16x8*)(wa + 0) = va0;
        *(bf16x8*)(wa + 8) = va1;
        *(bf16x8*)(wb + 0) = vb0;
        *(bf16x8*)(wb + 8) = vb1;
        __syncthreads();

        bf16x8 af[4], bfr[4];
#pragma unroll
        for (int i = 0; i < 4; ++i) af[i]  = *(const bf16x8*)(As + a_off[i]);
#pragma unroll
        for (int j = 0; j < 4; ++j) bfr[j] = *(const bf16x8*)(Bs + b_off[j]);

#pragma unroll
        for (int i = 0; i < 4; ++i)
#pragma unroll
            for (int j = 0; j < 4; ++j)
                acc[i][j] = __builtin_amdgcn_mfma_f32_16x16x32_bf16(
                    af[i], bfr[j], acc[i][j], 0, 0, 0);

        pa += FBK;
        pb += FBK;
    }

    const int orow0 = ti * 128 + wm * 64 + (lane >> 4) * 4;
    const int ocol0 = tj * 128 + wn * 64 + fm;
#pragma unroll
    for (int i = 0; i < 4; ++i)
#pragma unroll
        for (int j = 0; j < 4; ++j)
#pragma unroll
            for (int r = 0; r < 4; ++r)
                atomicAdd(out + (orow0 + i * 16 + r) * CDIM + ocol0 + j * 16,
                          acc[i][j][r]);
}

extern "C" void kernel_launch(void* const* d_in, const int* in_sizes, int n_in,
                              void* d_out, int out_size, void* d_ws, size_t ws_size,
                              hipStream_t stream) {
    const float* x = (const float*)d_in[0];
    float* out = (float*)d_out;
    const size_t need = (size_t)CDIM * HW * 2;   // 67,108,864 B bf16 copy

    hipMemsetAsync(d_out, 0, (size_t)out_size * sizeof(float), stream);

    if (ws_size >= need) {
        unsigned short* xb = (unsigned short*)d_ws;
        cvt_kernel<<<dim3(16384), dim3(256), 0, stream>>>(x, xb);
        gram_bf16_kernel<<<dim3(512), dim3(256), 0, stream>>>(xb, out);
        mirror_kernel<<<dim3(1024), dim3(256), 0, stream>>>(out);
    } else {
        gram_fallback<<<dim3(16, 32), dim3(256), 0, stream>>>(x, out);
    }
}